// Round 16
// baseline (46.369 us; speedup 1.0000x reference)
//
#include <hip/hip_runtime.h>

typedef float f32x4 __attribute__((ext_vector_type(4)));
typedef _Float16 f16x8 __attribute__((ext_vector_type(8)));
typedef __fp16 fp16x2 __attribute__((ext_vector_type(2)));

#define NEG_SLOPE 0.2f
#define MASK_EPS 1e-8f

// ---------------------------------------------------------------------------
// Kernel 1: pack (adj > eps) into transposed bitmask maskT[b][j][16 u32],
// float2-vectorized. Blocks with ic==0 also convert W -> wTf16 (f16 [n][k]).
// (R12-proven)
// ---------------------------------------------------------------------------
__global__ __launch_bounds__(256) void gat_mask_kernel(
    const float* __restrict__ adj, unsigned* __restrict__ maskT,
    const float* __restrict__ W, _Float16* __restrict__ wTf16) {
  const int b = blockIdx.x;            // 0..31
  const int ic = blockIdx.y;           // 0..15: 32-i word index
  const int tid = threadIdx.x;
  const int j = tid * 2;
  const float* ap = adj + (size_t)b * 262144 + (size_t)ic * 32 * 512 + j;
  unsigned w0 = 0, w1 = 0;
#pragma unroll
  for (int i = 0; i < 32; ++i) {
    float2 v = *(const float2*)(ap + (size_t)i * 512);
    w0 |= (v.x > MASK_EPS ? 1u : 0u) << i;
    w1 |= (v.y > MASK_EPS ? 1u : 0u) << i;
  }
  unsigned* mp = maskT + ((size_t)b * 512 + j) * 16 + ic;
  mp[0] = w0;
  mp[16] = w1;

  if (ic == 0) {                       // 32 blocks: W transpose+convert
    const int k = b * 4 + (tid >> 6);
    const int n = tid & 63;
    wTf16[(n) * 128 + k]      = (_Float16)W[k * 128 + n];
    wTf16[(n + 64) * 128 + k] = (_Float16)W[k * 128 + n + 64];
  }
}

// ---------------------------------------------------------------------------
// Kernel 2: Wh = h @ W via f16 MFMA. Zero LDS, zero barriers. (R7-proven)
// Epilogue writes whT in BLOCKED layout [b][h][it=16][dd=32][i32=32]
// (2KB contiguous 32x32 f16 tiles) so attn B-frag loads are coalesced.
// (R15-proven)
// ---------------------------------------------------------------------------
__global__ __launch_bounds__(256, 4) void gat_wh_mfma(
    const float* __restrict__ h, const _Float16* __restrict__ wTf16,
    const float* __restrict__ a, _Float16* __restrict__ whT,
    float* __restrict__ sIT, float* __restrict__ sJT) {
  const int tid = threadIdx.x;
  const int bid = blockIdx.x;          // 0..1023, 16 rows each
  const int w = tid >> 6;              // wave = head
  const int lane = tid & 63;
  const int nl = lane & 15;
  const int ig = lane >> 4;
  const int row0 = bid * 16;
  const int bb = row0 >> 9;
  const int iloc = row0 & 511;

  const float* hP = h + (size_t)(row0 + nl) * 128 + ig * 8;
  const _Float16* wP0 = wTf16 + (size_t)(w * 32 + nl) * 128 + ig * 8;
  const _Float16* wP1 = wTf16 + (size_t)(w * 32 + 16 + nl) * 128 + ig * 8;

  f32x4 acc0 = {0.f, 0.f, 0.f, 0.f};
  f32x4 acc1 = {0.f, 0.f, 0.f, 0.f};

#pragma unroll
  for (int kt = 0; kt < 4; ++kt) {
    f32x4 ha = *(const f32x4*)(hP + kt * 32);
    f32x4 hb = *(const f32x4*)(hP + kt * 32 + 4);
    union { fp16x2 h2[4]; f16x8 v; } af;
    af.h2[0] = __builtin_amdgcn_cvt_pkrtz(ha.x, ha.y);
    af.h2[1] = __builtin_amdgcn_cvt_pkrtz(ha.z, ha.w);
    af.h2[2] = __builtin_amdgcn_cvt_pkrtz(hb.x, hb.y);
    af.h2[3] = __builtin_amdgcn_cvt_pkrtz(hb.z, hb.w);
    const f16x8 b0 = *(const f16x8*)(wP0 + kt * 32);
    const f16x8 b1 = *(const f16x8*)(wP1 + kt * 32);
    acc0 = __builtin_amdgcn_mfma_f32_16x16x32_f16(af.v, b0, acc0, 0, 0, 0);
    acc1 = __builtin_amdgcn_mfma_f32_16x16x32_f16(af.v, b1, acc1, 0, 0, 0);
  }

  const float avS0 = a[w * 64 + nl];
  const float avS1 = a[w * 64 + 16 + nl];
  const float avD0 = a[w * 64 + 32 + nl];
  const float avD1 = a[w * 64 + 48 + nl];

  float si[4], sj[4];
#pragma unroll
  for (int reg = 0; reg < 4; ++reg) {
    si[reg] = acc0[reg] * avS0 + acc1[reg] * avS1;
    sj[reg] = acc0[reg] * avD0 + acc1[reg] * avD1;
#pragma unroll
    for (int off = 1; off < 16; off <<= 1) {
      si[reg] += __shfl_xor(si[reg], off, 64);
      sj[reg] += __shfl_xor(sj[reg], off, 64);
    }
  }
  if (nl == 0) {
    const int base = bb * 2048 + w * 512 + iloc + ig * 4;
#pragma unroll
    for (int reg = 0; reg < 4; ++reg) {
      sIT[base + reg] = si[reg];
      sJT[base + reg] = sj[reg];
    }
  }

  // blocked whT write: i_base = iloc + ig*4 (4 consecutive i in one tile)
  union { fp16x2 h2[2]; float2 f2; } p0, p1;
  p0.h2[0] = __builtin_amdgcn_cvt_pkrtz(acc0[0], acc0[1]);
  p0.h2[1] = __builtin_amdgcn_cvt_pkrtz(acc0[2], acc0[3]);
  p1.h2[0] = __builtin_amdgcn_cvt_pkrtz(acc1[0], acc1[1]);
  p1.h2[1] = __builtin_amdgcn_cvt_pkrtz(acc1[2], acc1[3]);
  const int i_base = iloc + ig * 4;
  const int it = i_base >> 5, i32 = i_base & 31;
  _Float16* wout = whT + (size_t)bb * 65536 + (size_t)w * 16384 + it * 1024 + i32;
  *(float2*)(wout + nl * 32)        = p0.f2;   // dd = nl
  *(float2*)(wout + (16 + nl) * 32) = p1.f2;   // dd = 16+nl
}

// ---------------------------------------------------------------------------
// Kernel 3: attention+aggregate (R6 structure + blocked whT reads).
// 256 thr = 4 waves = 4 heads; j-tile 16; grid (32 b fast, 32 jt) = 1024
// blocks. Zero LDS, zero barriers; mask bits in registers; per-step loads:
// si 2x16B + bf 2x16B, bf now 1KB-contiguous per wave (blocked layout).
// ---------------------------------------------------------------------------
__global__ __launch_bounds__(256, 4) void gat_attn_kernel(
    const unsigned* __restrict__ maskT, const _Float16* __restrict__ whT,
    const float* __restrict__ sIT, const float* __restrict__ sJT,
    float* __restrict__ out) {
  const int tid = threadIdx.x;
  const int b = blockIdx.x;            // 0..31 (fast: same-b -> same XCD)
  const int j0 = blockIdx.y * 16;      // 32 tiles
  const int wv = tid >> 6;             // wave = head
  const int lane = tid & 63;
  const int nl = lane & 15;
  const int ig = lane >> 4;

  const float sj = sJT[b * 2048 + wv * 512 + j0 + nl];

  const unsigned* mP = maskT + ((size_t)b * 512 + j0 + nl) * 16;
  uint4 mA = *(const uint4*)(mP);
  uint4 mB = *(const uint4*)(mP + 4);
  uint4 mC = *(const uint4*)(mP + 8);
  uint4 mD = *(const uint4*)(mP + 12);
  const unsigned mw[16] = {mA.x, mA.y, mA.z, mA.w, mB.x, mB.y, mB.z, mB.w,
                           mC.x, mC.y, mC.z, mC.w, mD.x, mD.y, mD.z, mD.w};

  // blocked whT: [b][hd][it=16][dd=32][i32=32]
  const _Float16* whP = whT + (size_t)b * 65536 + (size_t)wv * 16384 + nl * 32 + ig * 8;
  const float* siP = sIT + b * 2048 + wv * 512 + ig * 8;

  f32x4 acc0 = {0.f, 0.f, 0.f, 0.f};
  f32x4 acc1 = {0.f, 0.f, 0.f, 0.f};
  float l = 0.f;

#pragma unroll
  for (int t = 0; t < 8; ++t) {
#pragma unroll
    for (int ks = 0; ks < 2; ++ks) {
      const int st = t * 2 + ks;       // 32-i step 0..15
      f32x4 sA = *(const f32x4*)(siP + st * 32);
      f32x4 sB = *(const f32x4*)(siP + st * 32 + 4);
      const f16x8 bf0 = *(const f16x8*)(whP + st * 1024);        // dd = nl
      const f16x8 bf1 = *(const f16x8*)(whP + st * 1024 + 512);  // dd = 16+nl
      const unsigned bits = (mw[st] >> (ig * 8)) & 0xffu;

      float si[8] = {sA.x, sA.y, sA.z, sA.w, sB.x, sB.y, sB.z, sB.w};
      float p[8];
#pragma unroll
      for (int r = 0; r < 8; ++r) {
        float e = si[r] + sj;
        e = e >= 0.f ? e : NEG_SLOPE * e;
        p[r] = (bits & (1u << r)) ? __expf(e) : 0.f;
      }
      l += ((p[0] + p[1]) + (p[2] + p[3])) + ((p[4] + p[5]) + (p[6] + p[7]));

      union { fp16x2 h2[4]; f16x8 v; } af;
#pragma unroll
      for (int q = 0; q < 4; ++q)
        af.h2[q] = __builtin_amdgcn_cvt_pkrtz(p[2 * q], p[2 * q + 1]);

      acc0 = __builtin_amdgcn_mfma_f32_16x16x32_f16(af.v, bf0, acc0, 0, 0, 0);
      acc1 = __builtin_amdgcn_mfma_f32_16x16x32_f16(af.v, bf1, acc1, 0, 0, 0);
    }
  }

  // reduce l over the 4 ig-slices -> every lane has l for j = j0 + nl
  l += __shfl_xor(l, 16, 64);
  l += __shfl_xor(l, 32, 64);

  // D layout: row(m=j_local) = 4*ig + reg, col(n=d_lo) = nl
  float* outB = out + ((size_t)b * 512 + j0) * 128 + wv * 32;
#pragma unroll
  for (int reg = 0; reg < 4; ++reg) {
    const int jr = 4 * ig + reg;
    const float rl = 1.0f / __shfl(l, jr, 64);
    outB[(size_t)jr * 128 + nl]      = acc0[reg] * rl;
    outB[(size_t)jr * 128 + 16 + nl] = acc1[reg] * rl;
  }
}

extern "C" void kernel_launch(void* const* d_in, const int* in_sizes, int n_in,
                              void* d_out, int out_size, void* d_ws, size_t ws_size,
                              hipStream_t stream) {
  const float* h = (const float*)d_in[0];     // (32, 512, 128)
  const float* adj = (const float*)d_in[1];   // (32, 512, 512)
  const float* W = (const float*)d_in[2];     // (128, 128)
  const float* a = (const float*)d_in[3];     // (4, 64)
  float* out = (float*)d_out;                 // (32, 512, 128)

  _Float16* whT = (_Float16*)d_ws;                      // 4 MB (blocked layout)
  float* sIT = (float*)(whT + (size_t)32 * 128 * 512);  // 256 KB
  float* sJT = sIT + (size_t)32 * 4 * 512;              // 256 KB
  unsigned* maskT = (unsigned*)(sJT + (size_t)32 * 4 * 512);      // 1 MB
  _Float16* wTf16 = (_Float16*)(maskT + (size_t)32 * 512 * 16);   // 32 KB

  gat_mask_kernel<<<dim3(32, 16), dim3(256), 0, stream>>>(adj, maskT, W, wTf16);
  gat_wh_mfma<<<dim3(1024), dim3(256), 0, stream>>>(h, wTf16, a, whT, sIT, sJT);
  gat_attn_kernel<<<dim3(32, 32), dim3(256), 0, stream>>>(maskT, whT, sIT, sJT, out);
}